// Round 1
// baseline (711.467 us; speedup 1.0000x reference)
//
#include <hip/hip_runtime.h>

// Problem constants (match reference).
#define BB 32
#define MM 2048
#define NN 2048
#define ROWS 64      // rows of A per block
#define THREADS 256  // 4 waves

// ws layout (floats): [0, BB*NN) = At_lambda accumulator
//                     [BB*NN+0] = primal_sum, [+1] = comp_sum,
//                     [+2] = stat_sum,        [+3] = dual_sum

__device__ __forceinline__ float waveReduceSum(float v) {
#pragma unroll
    for (int off = 32; off > 0; off >>= 1)
        v += __shfl_down(v, off, 64);
    return v;  // valid in lane 0
}

__global__ __launch_bounds__(256) void zero_ws_kernel(float* __restrict__ ws, int n) {
    int i = blockIdx.x * blockDim.x + threadIdx.x;
    if (i < n) ws[i] = 0.0f;
}

// Fused single pass over A: per-row dot with x (-> primal/comp losses) and
// per-column accumulation with lam (-> At_lambda via atomics).
__global__ __launch_bounds__(THREADS) void fused_main(
    const float* __restrict__ x_hat, const float* __restrict__ lam_hat,
    const float* __restrict__ A, const float* __restrict__ b_pad,
    float* __restrict__ At, float* __restrict__ acc) {
    const int b = blockIdx.y;
    const int m0 = blockIdx.x * ROWS;
    const int t = threadIdx.x;
    const int wave = t >> 6;
    const int lane = t & 63;

    __shared__ float lamS[ROWS];
    __shared__ float wp[ROWS * 4];

    if (t < ROWS) lamS[t] = lam_hat[b * MM + m0 + t];
    __syncthreads();

    // Each thread owns columns [4t..4t+3] and [1024+4t..1024+4t+3].
    const float4* xv = (const float4*)(x_hat + (size_t)b * NN);
    const float4 x0 = xv[t];
    const float4 x1 = xv[256 + t];

    float4 at0 = make_float4(0.f, 0.f, 0.f, 0.f);
    float4 at1 = make_float4(0.f, 0.f, 0.f, 0.f);

    const float4* Ab = (const float4*)(A + ((size_t)b * MM + (size_t)m0) * NN);

    for (int r = 0; r < ROWS; ++r) {
        const float4* ap = Ab + (size_t)r * (NN / 4);
        float4 a0 = ap[t];
        float4 a1 = ap[256 + t];
        float lm = lamS[r];
        float dot = a0.x * x0.x + a0.y * x0.y + a0.z * x0.z + a0.w * x0.w
                  + a1.x * x1.x + a1.y * x1.y + a1.z * x1.z + a1.w * x1.w;
        at0.x += a0.x * lm; at0.y += a0.y * lm; at0.z += a0.z * lm; at0.w += a0.w * lm;
        at1.x += a1.x * lm; at1.y += a1.y * lm; at1.z += a1.z * lm; at1.w += a1.w * lm;
        float wsum = waveReduceSum(dot);
        if (lane == 0) wp[r * 4 + wave] = wsum;
    }
    __syncthreads();

    // Threads 0..63 (== wave 0) each finalize one row.
    if (t < ROWS) {
        int r = t;
        float y = wp[r * 4 + 0] + wp[r * 4 + 1] + wp[r * 4 + 2] + wp[r * 4 + 3]
                - b_pad[b * MM + m0 + r];
        float lm = lamS[r];
        float ry = fmaxf(y, 0.f);
        float pr = ry * ry;
        float cm = lm * y;
        cm = cm * cm;
        pr = waveReduceSum(pr);
        cm = waveReduceSum(cm);
        if (t == 0) {
            atomicAdd(&acc[0], pr);   // primal numerator
            atomicAdd(&acc[1], cm);   // comp numerator
        }
    }

    // Flush At_lambda partials (32 blocks contend per address).
    float* Atb = At + (size_t)b * NN;
    int c0 = t * 4;
    atomicAdd(&Atb[c0 + 0], at0.x);
    atomicAdd(&Atb[c0 + 1], at0.y);
    atomicAdd(&Atb[c0 + 2], at0.z);
    atomicAdd(&Atb[c0 + 3], at0.w);
    atomicAdd(&Atb[1024 + c0 + 0], at1.x);
    atomicAdd(&Atb[1024 + c0 + 1], at1.y);
    atomicAdd(&Atb[1024 + c0 + 2], at1.z);
    atomicAdd(&Atb[1024 + c0 + 3], at1.w);
}

// stat = sum (At + c)^2 over B*N ; dual = sum relu(-lam)^2 over B*M.
// (B*N == B*M == 65536, so one grid-stride loop covers both.)
__global__ __launch_bounds__(256) void finalize_partial(
    const float* __restrict__ At, const float* __restrict__ c_pad,
    const float* __restrict__ lam_hat, float* __restrict__ acc) {
    int idx = blockIdx.x * blockDim.x + threadIdx.x;
    int stride = gridDim.x * blockDim.x;
    float stat = 0.f, dual = 0.f;
    for (int i = idx; i < BB * NN; i += stride) {
        float v = At[i] + c_pad[i];
        stat += v * v;
        float l = lam_hat[i];
        float rn = fmaxf(-l, 0.f);
        dual += rn * rn;
    }
    stat = waveReduceSum(stat);
    dual = waveReduceSum(dual);
    __shared__ float s[8];
    int wave = threadIdx.x >> 6, lane = threadIdx.x & 63;
    if (lane == 0) { s[wave * 2 + 0] = stat; s[wave * 2 + 1] = dual; }
    __syncthreads();
    if (threadIdx.x == 0) {
        atomicAdd(&acc[2], s[0] + s[2] + s[4] + s[6]);
        atomicAdd(&acc[3], s[1] + s[3] + s[5] + s[7]);
    }
}

__global__ void combine_kernel(const float* __restrict__ acc, float* __restrict__ out) {
    const float invBM = 1.0f / (float)(BB * MM);
    const float invBN = 1.0f / (float)(BB * NN);
    float primal = acc[0] * invBM;
    float comp   = acc[1] * invBM;
    float stat   = acc[2] * invBN;
    float dual   = acc[3] * invBM;
    out[0] = 0.1f * primal + 0.1f * dual + 0.6f * stat + 0.2f * comp;
}

extern "C" void kernel_launch(void* const* d_in, const int* in_sizes, int n_in,
                              void* d_out, int out_size, void* d_ws, size_t ws_size,
                              hipStream_t stream) {
    const float* x_hat   = (const float*)d_in[0];
    const float* lam_hat = (const float*)d_in[1];
    const float* A       = (const float*)d_in[2];
    const float* b_pad   = (const float*)d_in[3];
    const float* c_pad   = (const float*)d_in[4];
    // d_in[5]/d_in[6] (masks) unused by the reference forward.
    float* out = (float*)d_out;

    float* At  = (float*)d_ws;
    float* acc = At + (size_t)BB * NN;

    const int ws_elems = BB * NN + 4;
    zero_ws_kernel<<<(ws_elems + 255) / 256, 256, 0, stream>>>((float*)d_ws, ws_elems);

    dim3 grid(MM / ROWS, BB);
    fused_main<<<grid, THREADS, 0, stream>>>(x_hat, lam_hat, A, b_pad, At, acc);

    finalize_partial<<<64, 256, 0, stream>>>(At, c_pad, lam_hat, acc);

    combine_kernel<<<1, 1, 0, stream>>>(acc, out);
}

// Round 3
// 664.035 us; speedup vs baseline: 1.0714x; 1.0714x over previous
//
#include <hip/hip_runtime.h>

// Problem constants (match reference).
#define BB 32
#define MM 2048
#define NN 2048
#define ROWS 64      // rows of A per block -> MM/ROWS = 32 chunks per batch
#define CHUNKS (MM / ROWS)
#define THREADS 256  // 4 waves

// Native vector type usable with __builtin_nontemporal_load.
typedef float f32x4 __attribute__((ext_vector_type(4)));

// ws layout (floats), all written-before-read (no zeroing needed):
//   [0, BB*CHUNKS*NN)                : At_lambda partials, [b][chunk][col]
//   P0 = BB*CHUNKS*NN, +2*BB*CHUNKS  : per-block {pr, cm} sums
//   P1 = P0 + 2*BB*CHUNKS, +64*4     : finalize per-block {stat,dual,pr,cm}
#define P0 ((size_t)BB * CHUNKS * NN)
#define P1 (P0 + 2 * BB * CHUNKS)
#define FIN_BLOCKS 64

__device__ __forceinline__ float waveReduceSum(float v) {
#pragma unroll
    for (int off = 32; off > 0; off >>= 1)
        v += __shfl_down(v, off, 64);
    return v;  // valid in lane 0
}

// Fused single pass over A: per-row dot with x (-> primal/comp partials) and
// per-column accumulation with lam (-> private At_lambda partial slice).
__global__ __launch_bounds__(THREADS) void fused_main(
    const float* __restrict__ x_hat, const float* __restrict__ lam_hat,
    const float* __restrict__ A, const float* __restrict__ b_pad,
    float* __restrict__ ws) {
    const int b = blockIdx.y;
    const int chunk = blockIdx.x;
    const int m0 = chunk * ROWS;
    const int t = threadIdx.x;
    const int wave = t >> 6;
    const int lane = t & 63;

    __shared__ float lamS[ROWS];
    __shared__ float wp[ROWS * 4];

    if (t < ROWS) lamS[t] = lam_hat[b * MM + m0 + t];
    __syncthreads();

    // Each thread owns columns [4t..4t+3] and [1024+4t..1024+4t+3].
    const f32x4* xv = (const f32x4*)(x_hat + (size_t)b * NN);
    const f32x4 x0 = xv[t];
    const f32x4 x1 = xv[256 + t];

    f32x4 at0 = (f32x4)(0.f);
    f32x4 at1 = (f32x4)(0.f);

    const f32x4* Ab = (const f32x4*)(A + ((size_t)b * MM + (size_t)m0) * NN);

    for (int r = 0; r < ROWS; ++r) {
        const f32x4* ap = Ab + (size_t)r * (NN / 4);
        f32x4 a0 = __builtin_nontemporal_load(ap + t);
        f32x4 a1 = __builtin_nontemporal_load(ap + 256 + t);
        float lm = lamS[r];
        f32x4 d = a0 * x0 + a1 * x1;
        float dot = d.x + d.y + d.z + d.w;
        at0 += a0 * lm;
        at1 += a1 * lm;
        float wsum = waveReduceSum(dot);
        if (lane == 0) wp[r * 4 + wave] = wsum;
    }
    __syncthreads();

    // Threads 0..63 (== wave 0) each finalize one row.
    if (t < ROWS) {
        int r = t;
        float y = wp[r * 4 + 0] + wp[r * 4 + 1] + wp[r * 4 + 2] + wp[r * 4 + 3]
                - b_pad[b * MM + m0 + r];
        float lm = lamS[r];
        float ry = fmaxf(y, 0.f);
        float pr = ry * ry;
        float cm = lm * y;
        cm = cm * cm;
        pr = waveReduceSum(pr);
        cm = waveReduceSum(cm);
        if (t == 0) {
            float* prcm = ws + P0 + ((size_t)b * CHUNKS + chunk) * 2;
            prcm[0] = pr;
            prcm[1] = cm;
        }
    }

    // Private-slice flush of the At_lambda partial (coalesced, no atomics).
    f32x4* dst = (f32x4*)(ws + ((size_t)b * CHUNKS + chunk) * NN);
    dst[t] = at0;
    dst[256 + t] = at1;
}

// Reduce 32 chunk-partials per column -> stat; plus dual and pr/cm partials.
// Writes per-block {stat,dual,pr,cm} to ws[P1 + blockIdx*4 ..].
__global__ __launch_bounds__(256) void finalize_partial(
    const float* __restrict__ ws_ro, const float* __restrict__ c_pad,
    const float* __restrict__ lam_hat, float* __restrict__ ws) {
    int idx = blockIdx.x * blockDim.x + threadIdx.x;
    int stride = gridDim.x * blockDim.x;
    float stat = 0.f, dual = 0.f, pr = 0.f, cm = 0.f;
    for (int i = idx; i < BB * NN; i += stride) {
        int b = i >> 11;          // / NN
        int col = i & (NN - 1);
        const float* p = ws_ro + (size_t)b * CHUNKS * NN + col;
        float s = 0.f;
#pragma unroll
        for (int k = 0; k < CHUNKS; ++k) s += p[(size_t)k * NN];
        float v = s + c_pad[i];
        stat += v * v;
        float l = lam_hat[i];
        float rn = fmaxf(-l, 0.f);
        dual += rn * rn;
    }
    for (int i = idx; i < BB * CHUNKS; i += stride) {
        pr += ws_ro[P0 + 2 * i];
        cm += ws_ro[P0 + 2 * i + 1];
    }
    stat = waveReduceSum(stat);
    dual = waveReduceSum(dual);
    pr = waveReduceSum(pr);
    cm = waveReduceSum(cm);
    __shared__ float s[16];
    int wave = threadIdx.x >> 6, lane = threadIdx.x & 63;
    if (lane == 0) {
        s[wave * 4 + 0] = stat; s[wave * 4 + 1] = dual;
        s[wave * 4 + 2] = pr;   s[wave * 4 + 3] = cm;
    }
    __syncthreads();
    if (threadIdx.x < 4) {
        float v = s[threadIdx.x] + s[4 + threadIdx.x] + s[8 + threadIdx.x] + s[12 + threadIdx.x];
        ws[P1 + (size_t)blockIdx.x * 4 + threadIdx.x] = v;
    }
}

// Reduce FIN_BLOCKS x {stat,dual,pr,cm} and apply loss weights.
__global__ __launch_bounds__(256) void combine_kernel(
    const float* __restrict__ ws_ro, float* __restrict__ out) {
    const int t = threadIdx.x;
    const int wave = t >> 6;   // category: 0=stat 1=dual 2=pr 3=cm
    const int lane = t & 63;
    float v = ws_ro[P1 + (size_t)lane * 4 + wave];  // FIN_BLOCKS == 64
    v = waveReduceSum(v);
    __shared__ float s[4];
    if (lane == 0) s[wave] = v;
    __syncthreads();
    if (t == 0) {
        const float invBM = 1.0f / (float)(BB * MM);
        const float invBN = 1.0f / (float)(BB * NN);
        float stat = s[0] * invBN;
        float dual = s[1] * invBM;
        float primal = s[2] * invBM;
        float comp = s[3] * invBM;
        out[0] = 0.1f * primal + 0.1f * dual + 0.6f * stat + 0.2f * comp;
    }
}

extern "C" void kernel_launch(void* const* d_in, const int* in_sizes, int n_in,
                              void* d_out, int out_size, void* d_ws, size_t ws_size,
                              hipStream_t stream) {
    const float* x_hat   = (const float*)d_in[0];
    const float* lam_hat = (const float*)d_in[1];
    const float* A       = (const float*)d_in[2];
    const float* b_pad   = (const float*)d_in[3];
    const float* c_pad   = (const float*)d_in[4];
    // d_in[5]/d_in[6] (masks) unused by the reference forward.
    float* out = (float*)d_out;
    float* ws = (float*)d_ws;

    dim3 grid(CHUNKS, BB);
    fused_main<<<grid, THREADS, 0, stream>>>(x_hat, lam_hat, A, b_pad, ws);

    finalize_partial<<<FIN_BLOCKS, 256, 0, stream>>>(ws, c_pad, lam_hat, ws);

    combine_kernel<<<1, 256, 0, stream>>>(ws, out);
}